// Round 1
// baseline (158.673 us; speedup 1.0000x reference)
//
#include <hip/hip_runtime.h>

#define NQ 12
#define NSTATE (1 << NQ)     // 4096
#define NL 6
#define TPB 256
#define APT (NSTATE / TPB)   // 16 amps per thread
#define PPT (NSTATE / 2 / TPB) // 8 pairs per thread

// One workgroup per batch element. State vector (4096 complex f32) lives in LDS.
// Init: product state from RX embedding (amp_i = m_i * (-i)^popcount(i)).
// Layer: 12 generic 2x2 complex gate passes + one Gray-code permutation pass
//        (the CNOT chain CNOT(0,1)..CNOT(10,11) composes to new[i]=old[i^(i>>1)]).
// Measure: z = sum_i sign(bit11(i)) * |amp_i|^2, then 2-wide linear head.
__global__ __launch_bounds__(TPB) void qsim_kernel(
    const float* __restrict__ x,      // (B, 12)
    const float* __restrict__ w,      // (6, 12, 3)
    const float* __restrict__ hw,     // (2, 1)
    const float* __restrict__ hb,     // (2,)
    float* __restrict__ out)          // (B, 2)
{
    __shared__ float2 st[NSTATE];     // 32 KB state
    __shared__ float2 U[NQ][4];       // current layer's gate matrices
    __shared__ float  csq[NQ][2];     // cos/sin of x/2 per qubit
    __shared__ float  red[TPB / 64];  // cross-wave reduction

    const int b = blockIdx.x;
    const int t = threadIdx.x;

    // --- embedding angles ---
    if (t < NQ) {
        float h = 0.5f * x[b * NQ + t];
        float sh, ch;
        sincosf(h, &sh, &ch);
        csq[t][0] = ch;   // bit=0 factor magnitude
        csq[t][1] = sh;   // bit=1 factor magnitude (phase -i handled below)
    }
    __syncthreads();

    // --- init product state: amp_i = (-i)^popc(i) * prod_q (bit_q ? sin : cos) ---
    #pragma unroll
    for (int j = 0; j < APT; ++j) {
        int i = t + j * TPB;
        float m = 1.0f;
        #pragma unroll
        for (int q = 0; q < NQ; ++q)          // qubit q <-> bit (11-q)
            m *= csq[q][(i >> (NQ - 1 - q)) & 1];
        int pc = __popc(i) & 3;
        float2 a;
        a.x = (pc == 0) ? m : ((pc == 2) ? -m : 0.0f);
        a.y = (pc == 1) ? -m : ((pc == 3) ? m : 0.0f);
        st[i] = a;
    }
    __syncthreads();

    // --- layers ---
    for (int L = 0; L < NL; ++L) {
        // Rot(phi, theta, omega) matrices for this layer (threads 0..11)
        if (t < NQ) {
            const float* wl = w + (L * NQ + t) * 3;
            float phi = wl[0], th = wl[1], om = wl[2];
            float c, s, ca, sa, cb, sb;
            sincosf(0.5f * th, &s, &c);
            sincosf(0.5f * (phi + om), &sa, &ca);
            sincosf(0.5f * (phi - om), &sb, &cb);
            U[t][0] = make_float2( c * ca, -c * sa);   // ep*c
            U[t][1] = make_float2(-s * cb, -s * sb);   // -conj(em)*s
            U[t][2] = make_float2( s * cb, -s * sb);   // em*s
            U[t][3] = make_float2( c * ca,  c * sa);   // conj(ep)*c
        }
        __syncthreads();

        // 12 single-qubit gate passes
        #pragma unroll
        for (int g = 0; g < NQ; ++g) {
            const int p = NQ - 1 - g;             // bit position of qubit g
            float2 u00 = U[g][0], u01 = U[g][1], u10 = U[g][2], u11 = U[g][3];
            #pragma unroll
            for (int j = 0; j < PPT; ++j) {
                int k  = t + j * TPB;             // pair index 0..2047
                int lo = k & ((1 << p) - 1);
                int i0 = ((k ^ lo) << 1) | lo;    // insert 0 at bit p
                int i1 = i0 | (1 << p);
                float2 s0 = st[i0], s1 = st[i1];
                float2 n0, n1;
                n0.x = u00.x*s0.x - u00.y*s0.y + u01.x*s1.x - u01.y*s1.y;
                n0.y = u00.x*s0.y + u00.y*s0.x + u01.x*s1.y + u01.y*s1.x;
                n1.x = u10.x*s0.x - u10.y*s0.y + u11.x*s1.x - u11.y*s1.y;
                n1.y = u10.x*s0.y + u10.y*s0.x + u11.x*s1.y + u11.y*s1.x;
                st[i0] = n0;
                st[i1] = n1;
            }
            __syncthreads();
        }

        // CNOT chain == Gray-code permutation: new[i] = old[i ^ (i>>1)]
        float2 tmp[APT];
        #pragma unroll
        for (int j = 0; j < APT; ++j) {
            int i = t + j * TPB;
            tmp[j] = st[i ^ (i >> 1)];
        }
        __syncthreads();
        #pragma unroll
        for (int j = 0; j < APT; ++j)
            st[t + j * TPB] = tmp[j];
        __syncthreads();
    }

    // --- measurement: <Z> on qubit 0 (bit 11) ---
    float z = 0.0f;
    #pragma unroll
    for (int j = 0; j < APT; ++j) {
        int i = t + j * TPB;
        float2 a = st[i];
        float p2 = a.x * a.x + a.y * a.y;
        z += (i & (NSTATE >> 1)) ? -p2 : p2;
    }
    #pragma unroll
    for (int off = 32; off >= 1; off >>= 1)
        z += __shfl_down(z, off);
    if ((t & 63) == 0) red[t >> 6] = z;
    __syncthreads();

    if (t == 0) {
        float zt = 0.0f;
        #pragma unroll
        for (int wv = 0; wv < TPB / 64; ++wv) zt += red[wv];
        out[2 * b + 0] = zt * hw[0] + hb[0];
        out[2 * b + 1] = zt * hw[1] + hb[1];
    }
}

extern "C" void kernel_launch(void* const* d_in, const int* in_sizes, int n_in,
                              void* d_out, int out_size, void* d_ws, size_t ws_size,
                              hipStream_t stream) {
    const float* x  = (const float*)d_in[0];
    const float* w  = (const float*)d_in[1];
    const float* hw = (const float*)d_in[2];
    const float* hb = (const float*)d_in[3];
    float* out = (float*)d_out;
    const int B = in_sizes[0] / NQ;   // 1024
    qsim_kernel<<<B, TPB, 0, stream>>>(x, w, hw, hb, out);
}

// Round 2
// 137.760 us; speedup vs baseline: 1.1518x; 1.1518x over previous
//
#include <hip/hip_runtime.h>

#define NQ 12
#define NSTATE (1 << NQ)   // 4096
#define NL 6
#define TPB 256
#define NREG 16            // amplitudes per thread

// LDS bank swizzle: physical = i ^ ((i>>4)&0xF).  For all three pass
// partitions (reg nibble = bits 11-8 / 7-4 / 3-0) the 64 lanes of a wave map
// onto all 16 bank-pairs exactly 4x per ds_*_b64 -> minimal (conflict-free).
__device__ __forceinline__ int swz(int i) { return i ^ ((i >> 4) & 0xF); }

__device__ __forceinline__ void butterfly(float2& s0, float2& s1,
                                          float2 u00, float2 u01,
                                          float2 u10, float2 u11) {
    float2 n0, n1;
    n0.x = u00.x*s0.x - u00.y*s0.y + u01.x*s1.x - u01.y*s1.y;
    n0.y = u00.x*s0.y + u00.y*s0.x + u01.x*s1.y + u01.y*s1.x;
    n1.x = u10.x*s0.x - u10.y*s0.y + u11.x*s1.x - u11.y*s1.y;
    n1.y = u10.x*s0.y + u10.y*s0.x + u11.x*s1.y + u11.y*s1.x;
    s0 = n0; s1 = n1;
}

// One workgroup per batch element; state in LDS; 4 gates per LDS round-trip.
// Layer = 3 passes (bits 11-8, 7-4, 3-0). CNOT chain == Gray-code permutation
// new[i]=old[i^(i>>1)], fused into the NEXT layer's pass-A load. The final
// permutation preserves bit 11, so measurement skips it and stays in regs.
__global__ __launch_bounds__(TPB, 4) void qsim_kernel(
    const float* __restrict__ x,      // (B, 12)
    const float* __restrict__ w,      // (6, 12, 3)
    const float* __restrict__ hw,     // (2, 1)
    const float* __restrict__ hb,     // (2,)
    float* __restrict__ out)          // (B, 2)
{
    __shared__ float2 st[NSTATE];     // 32 KB state (swizzled addressing)
    __shared__ float2 U[NL][NQ][4];   // all gate matrices, computed once
    __shared__ float  csq[NQ][2];     // cos/sin of x/2 per qubit
    __shared__ float  red[TPB / 64];

    const int b = blockIdx.x;
    const int t = threadIdx.x;

    // --- all 72 Rot matrices up front (threads 0..71) ---
    if (t < NL * NQ) {
        int L = t / NQ, q = t % NQ;
        const float* wl = w + (L * NQ + q) * 3;
        float phi = wl[0], th = wl[1], om = wl[2];
        float c, s, ca, sa, cb, sb;
        sincosf(0.5f * th, &s, &c);
        sincosf(0.5f * (phi + om), &sa, &ca);
        sincosf(0.5f * (phi - om), &sb, &cb);
        U[L][q][0] = make_float2( c * ca, -c * sa);   // ep*c
        U[L][q][1] = make_float2(-s * cb, -s * sb);   // -conj(em)*s
        U[L][q][2] = make_float2( s * cb, -s * sb);   // em*s
        U[L][q][3] = make_float2( c * ca,  c * sa);   // conj(ep)*c
    }
    // --- embedding angles (threads 128..139, parallel wave) ---
    if (t >= 128 && t < 128 + NQ) {
        int q = t - 128;
        float h = 0.5f * x[b * NQ + q];
        float sh, ch;
        sincosf(h, &sh, &ch);
        csq[q][0] = ch;
        csq[q][1] = sh;
    }
    __syncthreads();

    float2 a[NREG];

    for (int L = 0; L < NL; ++L) {
        // ======== Pass A: state bits 11..8 (qubits 0..3), i = (r<<8)|t ========
        if (L == 0) {
            // init product state directly in registers:
            // amp_i = (-i)^popc(i) * prod_q (bit_q ? sin : cos)
            float mlow = 1.0f;
            #pragma unroll
            for (int q = 4; q < NQ; ++q)          // qubit q <-> bit 11-q (in t)
                mlow *= csq[q][(t >> (11 - q)) & 1];
            int pcl = __popc(t);
            #pragma unroll
            for (int r = 0; r < NREG; ++r) {
                float m = mlow;
                #pragma unroll
                for (int k = 0; k < 4; ++k)       // r bit k = state bit 8+k = qubit 3-k
                    m *= csq[3 - k][(r >> k) & 1];
                int pc = (pcl + __popc(r)) & 3;
                a[r].x = (pc == 0) ? m : ((pc == 2) ? -m : 0.0f);
                a[r].y = (pc == 1) ? -m : ((pc == 3) ? m : 0.0f);
            }
        } else {
            #pragma unroll
            for (int r = 0; r < NREG; ++r) {
                int i  = (r << 8) | t;
                int gi = i ^ (i >> 1);            // fused CNOT-chain permutation
                a[r] = st[swz(gi)];
            }
            __syncthreads();   // all reads done before anyone overwrites below
        }
        #pragma unroll
        for (int k = 0; k < 4; ++k) {
            const int q = 3 - k;
            float2 u00 = U[L][q][0], u01 = U[L][q][1];
            float2 u10 = U[L][q][2], u11 = U[L][q][3];
            #pragma unroll
            for (int r = 0; r < NREG; ++r)
                if (!(r & (1 << k)))
                    butterfly(a[r], a[r | (1 << k)], u00, u01, u10, u11);
        }
        #pragma unroll
        for (int r = 0; r < NREG; ++r)
            st[swz((r << 8) | t)] = a[r];
        __syncthreads();

        // ======== Pass B: state bits 7..4 (qubits 4..7) ========
        const int ibase_b = ((t & 0xF0) << 4) | (t & 0x0F);
        #pragma unroll
        for (int r = 0; r < NREG; ++r)
            a[r] = st[swz(ibase_b | (r << 4))];
        #pragma unroll
        for (int k = 0; k < 4; ++k) {
            const int q = 7 - k;
            float2 u00 = U[L][q][0], u01 = U[L][q][1];
            float2 u10 = U[L][q][2], u11 = U[L][q][3];
            #pragma unroll
            for (int r = 0; r < NREG; ++r)
                if (!(r & (1 << k)))
                    butterfly(a[r], a[r | (1 << k)], u00, u01, u10, u11);
        }
        #pragma unroll
        for (int r = 0; r < NREG; ++r)
            st[swz(ibase_b | (r << 4))] = a[r];
        __syncthreads();

        // ======== Pass C: state bits 3..0 (qubits 8..11), i = (t<<4)|r ========
        #pragma unroll
        for (int r = 0; r < NREG; ++r)
            a[r] = st[swz((t << 4) | r)];
        #pragma unroll
        for (int k = 0; k < 4; ++k) {
            const int q = 11 - k;
            float2 u00 = U[L][q][0], u01 = U[L][q][1];
            float2 u10 = U[L][q][2], u11 = U[L][q][3];
            #pragma unroll
            for (int r = 0; r < NREG; ++r)
                if (!(r & (1 << k)))
                    butterfly(a[r], a[r | (1 << k)], u00, u01, u10, u11);
        }
        if (L < NL - 1) {
            #pragma unroll
            for (int r = 0; r < NREG; ++r)
                st[swz((t << 4) | r)] = a[r];
            __syncthreads();
        }
        // last layer: state stays in registers for measurement (the trailing
        // Gray permutation preserves bit 11, so it is measurement-invariant)
    }

    // --- measurement: <Z> on qubit 0 (state bit 11 = t bit 7) ---
    float zsum = 0.0f;
    #pragma unroll
    for (int r = 0; r < NREG; ++r)
        zsum += a[r].x * a[r].x + a[r].y * a[r].y;
    float z = (t & 0x80) ? -zsum : zsum;
    #pragma unroll
    for (int off = 32; off >= 1; off >>= 1)
        z += __shfl_down(z, off);
    if ((t & 63) == 0) red[t >> 6] = z;
    __syncthreads();

    if (t == 0) {
        float zt = red[0] + red[1] + red[2] + red[3];
        out[2 * b + 0] = zt * hw[0] + hb[0];
        out[2 * b + 1] = zt * hw[1] + hb[1];
    }
}

extern "C" void kernel_launch(void* const* d_in, const int* in_sizes, int n_in,
                              void* d_out, int out_size, void* d_ws, size_t ws_size,
                              hipStream_t stream) {
    const float* x  = (const float*)d_in[0];
    const float* w  = (const float*)d_in[1];
    const float* hw = (const float*)d_in[2];
    const float* hb = (const float*)d_in[3];
    float* out = (float*)d_out;
    const int B = in_sizes[0] / NQ;   // 1024
    qsim_kernel<<<B, TPB, 0, stream>>>(x, w, hw, hb, out);
}

// Round 3
// 113.545 us; speedup vs baseline: 1.3974x; 1.2133x over previous
//
#include <hip/hip_runtime.h>

#define NQ 12
#define NSTATE (1 << NQ)   // 4096
#define NL 6
#define TPB 256

// LDS bank swizzle (GF(2)-linear): phys = i ^ ((i>>4)&0xF)
__device__ __forceinline__ int swz(int i) { return i ^ ((i >> 4) & 0xF); }

// g^L where g(i) = i ^ (i>>1) (the CNOT-chain permutation, linear over GF(2)).
// g = I + S (S = shift-right); g^L = XOR of S^k over k submask of L (Lucas).
__device__ __forceinline__ int gp(int x, int L) {
    int v = x;
    if (L & 1) v ^= x >> 1;
    if (L & 2) v ^= x >> 2;
    if ((L & 3) == 3) v ^= x >> 3;
    if (L & 4) v ^= x >> 4;
    if ((L & 5) == 5) v ^= x >> 5;
    return v;
}

__device__ __forceinline__ void butterfly(float2& s0, float2& s1,
                                          float2 u00, float2 u01,
                                          float2 u10, float2 u11) {
    float2 n0, n1;
    n0.x = u00.x*s0.x - u00.y*s0.y + u01.x*s1.x - u01.y*s1.y;
    n0.y = u00.x*s0.y + u00.y*s0.x + u01.x*s1.y + u01.y*s1.x;
    n1.x = u10.x*s0.x - u10.y*s0.y + u11.x*s1.x - u11.y*s1.y;
    n1.y = u10.x*s0.y + u10.y*s0.x + u11.x*s1.y + u11.y*s1.x;
    s0 = n0; s1 = n1;
}

// 16 named state registers (a0..a15) — literal indices only, guaranteed VGPRs.
#define BF(i,j) butterfly(a##i, a##j, u00, u01, u10, u11)
#define PAIRS0 BF(0,1);BF(2,3);BF(4,5);BF(6,7);BF(8,9);BF(10,11);BF(12,13);BF(14,15);
#define PAIRS1 BF(0,2);BF(1,3);BF(4,6);BF(5,7);BF(8,10);BF(9,11);BF(12,14);BF(13,15);
#define PAIRS2 BF(0,4);BF(1,5);BF(2,6);BF(3,7);BF(8,12);BF(9,13);BF(10,14);BF(11,15);
#define PAIRS3 BF(0,8);BF(1,9);BF(2,10);BF(3,11);BF(4,12);BF(5,13);BF(6,14);BF(7,15);
#define GATE(q, PAIRS) { float2 u00=U[L][q][0], u01=U[L][q][1], \
                                u10=U[L][q][2], u11=U[L][q][3]; PAIRS }
// reg bit k <-> qubit (qb + 3 - k); same-layer 1q gates commute, order free
#define GATES4(qb) GATE((qb)+3, PAIRS0) GATE((qb)+2, PAIRS1) \
                   GATE((qb)+1, PAIRS2) GATE((qb)+0, PAIRS3)

#define LD16(A) { a0=st[A(0)]; a1=st[A(1)]; a2=st[A(2)]; a3=st[A(3)]; \
                  a4=st[A(4)]; a5=st[A(5)]; a6=st[A(6)]; a7=st[A(7)]; \
                  a8=st[A(8)]; a9=st[A(9)]; a10=st[A(10)]; a11=st[A(11)]; \
                  a12=st[A(12)]; a13=st[A(13)]; a14=st[A(14)]; a15=st[A(15)]; }
#define ST16(A) { st[A(0)]=a0; st[A(1)]=a1; st[A(2)]=a2; st[A(3)]=a3; \
                  st[A(4)]=a4; st[A(5)]=a5; st[A(6)]=a6; st[A(7)]=a7; \
                  st[A(8)]=a8; st[A(9)]=a9; st[A(10)]=a10; st[A(11)]=a11; \
                  st[A(12)]=a12; st[A(13)]=a13; st[A(14)]=a14; st[A(15)]=a15; }

// per-pass addresses: phys(i) = swz(g^L(i)); linear => lane-part ^ reg-basis XORs
#define MXA(r) ((((r)&1)?MA_0:0) ^ (((r)&2)?MA_1:0) ^ (((r)&4)?MA_2:0) ^ (((r)&8)?MA_3:0))
#define MXB(r) ((((r)&1)?MB_0:0) ^ (((r)&2)?MB_1:0) ^ (((r)&4)?MB_2:0) ^ (((r)&8)?MB_3:0))
#define MXC(r) ((((r)&1)?MC_0:0) ^ (((r)&2)?MC_1:0) ^ (((r)&4)?MC_2:0) ^ (((r)&8)?MC_3:0))
#define ADRA(r) (ptA ^ MXA(r))
#define ADRB(r) (ptB ^ MXB(r))
#define ADRC(r) (ptC ^ MXC(r))

#define INITR(r) { float m = mlow; \
    m *= csq[3][(r)&1]; m *= csq[2][((r)>>1)&1]; \
    m *= csq[1][((r)>>2)&1]; m *= csq[0][((r)>>3)&1]; \
    const int pc = (pcl + __popc(r)) & 3; \
    a##r = make_float2((pc==0) ? m : ((pc==2) ? -m : 0.0f), \
                       (pc==1) ? -m : ((pc==3) ? m : 0.0f)); }

// One workgroup per batch element; state (4096 c64) in LDS; 4 gates per LDS
// round-trip; CNOT-chain Gray permutations absorbed into layout tracking
// (layer L addresses through g^L) — zero data movement, 1 barrier per pass.
__global__ __launch_bounds__(TPB, 4) void qsim_kernel(
    const float* __restrict__ x,      // (B, 12)
    const float* __restrict__ w,      // (6, 12, 3)
    const float* __restrict__ hw,     // (2, 1)
    const float* __restrict__ hb,     // (2,)
    float* __restrict__ out)          // (B, 2)
{
    __shared__ float2 st[NSTATE];     // 32 KB
    __shared__ float2 U[NL][NQ][4];
    __shared__ float  csq[NQ][2];
    __shared__ float  red[TPB / 64];

    const int b = blockIdx.x;
    const int t = threadIdx.x;

    // --- all 72 Rot matrices (threads 0..71) ---
    if (t < NL * NQ) {
        int L = t / NQ, q = t % NQ;
        const float* wl = w + (L * NQ + q) * 3;
        float phi = wl[0], th = wl[1], om = wl[2];
        float c, s, ca, sa, cb, sb;
        sincosf(0.5f * th, &s, &c);
        sincosf(0.5f * (phi + om), &sa, &ca);
        sincosf(0.5f * (phi - om), &sb, &cb);
        U[L][q][0] = make_float2( c * ca, -c * sa);   // ep*c
        U[L][q][1] = make_float2(-s * cb, -s * sb);   // -conj(em)*s
        U[L][q][2] = make_float2( s * cb, -s * sb);   // em*s
        U[L][q][3] = make_float2( c * ca,  c * sa);   // conj(ep)*c
    }
    // --- embedding angles (threads 128..139, runs in parallel wave) ---
    if (t >= 128 && t < 128 + NQ) {
        int q = t - 128;
        float h = 0.5f * x[b * NQ + q];
        float sh, ch;
        sincosf(h, &sh, &ch);
        csq[q][0] = ch;
        csq[q][1] = sh;
    }
    __syncthreads();

    float2 a0,a1,a2,a3,a4,a5,a6,a7,a8,a9,a10,a11,a12,a13,a14,a15;

    #pragma unroll 1
    for (int L = 0; L < NL; ++L) {
        // reg-nibble basis images under swz∘g^L (thread-uniform -> SALU)
        const int MA_0 = swz(gp(0x100, L)), MA_1 = swz(gp(0x200, L)),
                  MA_2 = swz(gp(0x400, L)), MA_3 = swz(gp(0x800, L));
        const int MB_0 = swz(gp(0x010, L)), MB_1 = swz(gp(0x020, L)),
                  MB_2 = swz(gp(0x040, L)), MB_3 = swz(gp(0x080, L));
        const int MC_0 = swz(gp(0x001, L)), MC_1 = swz(gp(0x002, L)),
                  MC_2 = swz(gp(0x004, L)), MC_3 = swz(gp(0x008, L));

        // ======== Pass A: logical i = (r<<8)|t  (qubits 0..3) ========
        const int ptA = swz(gp(t, L));
        if (L == 0) {
            // init product state in regs: amp_i = (-i)^popc(i) * prod(cos/sin)
            float mlow = 1.0f;
            #pragma unroll
            for (int q = 4; q < NQ; ++q)
                mlow *= csq[q][(t >> (11 - q)) & 1];
            const int pcl = __popc(t);
            INITR(0)  INITR(1)  INITR(2)  INITR(3)
            INITR(4)  INITR(5)  INITR(6)  INITR(7)
            INITR(8)  INITR(9)  INITR(10) INITR(11)
            INITR(12) INITR(13) INITR(14) INITR(15)
        } else {
            LD16(ADRA)
        }
        GATES4(0)
        ST16(ADRA)
        __syncthreads();

        // ======== Pass B: logical i = t[7:4]<<8 | r<<4 | t[3:0] (qubits 4..7) ====
        const int ptB = swz(gp(((t & 0xF0) << 4) | (t & 0x0F), L));
        LD16(ADRB)
        GATES4(4)
        ST16(ADRB)
        __syncthreads();

        // ======== Pass C: logical i = (t<<4)|r  (qubits 8..11) ========
        const int ptC = swz(gp(t << 4, L));
        LD16(ADRC)
        GATES4(8)
        if (L < NL - 1) {
            ST16(ADRC)
            __syncthreads();
        }
        // last layer: measurement reads the regs; trailing Gray perm preserves
        // state bit 11, so it cannot change <Z_0>.
    }

    // --- measurement: <Z> on qubit 0 = state bit 11 = t bit 7 ---
    float zsum = 0.0f;
    zsum += a0.x*a0.x + a0.y*a0.y;     zsum += a1.x*a1.x + a1.y*a1.y;
    zsum += a2.x*a2.x + a2.y*a2.y;     zsum += a3.x*a3.x + a3.y*a3.y;
    zsum += a4.x*a4.x + a4.y*a4.y;     zsum += a5.x*a5.x + a5.y*a5.y;
    zsum += a6.x*a6.x + a6.y*a6.y;     zsum += a7.x*a7.x + a7.y*a7.y;
    zsum += a8.x*a8.x + a8.y*a8.y;     zsum += a9.x*a9.x + a9.y*a9.y;
    zsum += a10.x*a10.x + a10.y*a10.y; zsum += a11.x*a11.x + a11.y*a11.y;
    zsum += a12.x*a12.x + a12.y*a12.y; zsum += a13.x*a13.x + a13.y*a13.y;
    zsum += a14.x*a14.x + a14.y*a14.y; zsum += a15.x*a15.x + a15.y*a15.y;

    float z = (t & 0x80) ? -zsum : zsum;
    #pragma unroll
    for (int off = 32; off >= 1; off >>= 1)
        z += __shfl_down(z, off);
    if ((t & 63) == 0) red[t >> 6] = z;
    __syncthreads();

    if (t == 0) {
        float zt = red[0] + red[1] + red[2] + red[3];
        out[2 * b + 0] = zt * hw[0] + hb[0];
        out[2 * b + 1] = zt * hw[1] + hb[1];
    }
}

extern "C" void kernel_launch(void* const* d_in, const int* in_sizes, int n_in,
                              void* d_out, int out_size, void* d_ws, size_t ws_size,
                              hipStream_t stream) {
    const float* x  = (const float*)d_in[0];
    const float* w  = (const float*)d_in[1];
    const float* hw = (const float*)d_in[2];
    const float* hb = (const float*)d_in[3];
    float* out = (float*)d_out;
    const int B = in_sizes[0] / NQ;   // 1024
    qsim_kernel<<<B, TPB, 0, stream>>>(x, w, hw, hb, out);
}

// Round 4
// 102.954 us; speedup vs baseline: 1.5412x; 1.1029x over previous
//
#include <hip/hip_runtime.h>

#define NQ 12
#define NSTATE (1 << NQ)   // 4096
#define NL 6
#define TPB 256

// Fixed LDS layout: phys = swz(i) = i ^ ((i>>4)&0xF)  (GF(2)-linear).
// The CNOT-chain Gray permutation new[i]=old[i^(i>>1)] is absorbed by loading
// the NEXT layer's pass A at swz(g(i)), g(i)=i^(i>>1). All six lane->bank-pair
// maps (3 store/load patterns + the g-composed pass-A load) are rank-4 over
// the wave's 6 lane bits => conflict-free (4 lanes per bank-pair, b64 minimum).

__device__ __forceinline__ void butterfly(float2& s0, float2& s1,
                                          float2 u00, float2 u01,
                                          float2 u10, float2 u11) {
    float2 n0, n1;
    n0.x = u00.x*s0.x - u00.y*s0.y + u01.x*s1.x - u01.y*s1.y;
    n0.y = u00.x*s0.y + u00.y*s0.x + u01.x*s1.y + u01.y*s1.x;
    n1.x = u10.x*s0.x - u10.y*s0.y + u11.x*s1.x - u11.y*s1.y;
    n1.y = u10.x*s0.y + u10.y*s0.x + u11.x*s1.y + u11.y*s1.x;
    s0 = n0; s1 = n1;
}

// 16 named state registers — literal indices only => guaranteed VGPRs.
#define BF(i,j) butterfly(a##i, a##j, u00, u01, u10, u11)
#define PAIRS0 BF(0,1);BF(2,3);BF(4,5);BF(6,7);BF(8,9);BF(10,11);BF(12,13);BF(14,15);
#define PAIRS1 BF(0,2);BF(1,3);BF(4,6);BF(5,7);BF(8,10);BF(9,11);BF(12,14);BF(13,15);
#define PAIRS2 BF(0,4);BF(1,5);BF(2,6);BF(3,7);BF(8,12);BF(9,13);BF(10,14);BF(11,15);
#define PAIRS3 BF(0,8);BF(1,9);BF(2,10);BF(3,11);BF(4,12);BF(5,13);BF(6,14);BF(7,15);
#define GATE(q, PAIRS) { float2 u00=U[L][q][0], u01=U[L][q][1], \
                                u10=U[L][q][2], u11=U[L][q][3]; PAIRS }
// reg bit k <-> qubit (qb + 3 - k); same-layer 1q gates commute
#define GATES4(qb) GATE((qb)+3, PAIRS0) GATE((qb)+2, PAIRS1) \
                   GATE((qb)+1, PAIRS2) GATE((qb)+0, PAIRS3)

#define LD16(A) { a0=st[A(0)]; a1=st[A(1)]; a2=st[A(2)]; a3=st[A(3)]; \
                  a4=st[A(4)]; a5=st[A(5)]; a6=st[A(6)]; a7=st[A(7)]; \
                  a8=st[A(8)]; a9=st[A(9)]; a10=st[A(10)]; a11=st[A(11)]; \
                  a12=st[A(12)]; a13=st[A(13)]; a14=st[A(14)]; a15=st[A(15)]; }
#define ST16(A) { st[A(0)]=a0; st[A(1)]=a1; st[A(2)]=a2; st[A(3)]=a3; \
                  st[A(4)]=a4; st[A(5)]=a5; st[A(6)]=a6; st[A(7)]=a7; \
                  st[A(8)]=a8; st[A(9)]=a9; st[A(10)]=a10; st[A(11)]=a11; \
                  st[A(12)]=a12; st[A(13)]=a13; st[A(14)]=a14; st[A(15)]=a15; }

// Pass A store:  i=(r<<8)|t          -> phys = (r<<8) | swz(t)
// Pass A load:   phys = swz(g(i))    = swz(g(t)) ^ [ (r<<8)^(r<<7)^((r&1)<<3) ]
// Pass B:        i=t[7:4]<<8|r<<4|t[3:0] -> phys = ptB ^ (r<<4) ^ r
// Pass C:        i=(t<<4)|r          -> phys = ptC ^ r
#define ADRA_ST(r) (swzt | ((r) << 8))
#define GAC(r)     ((((r) << 8) ^ ((r) << 7) ^ (((r) & 1) << 3)))
#define ADRA_LD(r) (gswzt ^ GAC(r))
#define ADRB(r)    (ptB ^ ((r) << 4) ^ (r))
#define ADRC(r)    (ptC ^ (r))

#define INITR(r) { float m = mlow; \
    m *= csq[3][(r)&1]; m *= csq[2][((r)>>1)&1]; \
    m *= csq[1][((r)>>2)&1]; m *= csq[0][((r)>>3)&1]; \
    const int pc = (pcl + __popc(r)) & 3; \
    a##r = make_float2((pc==0) ? m : ((pc==2) ? -m : 0.0f), \
                       (pc==1) ? -m : ((pc==3) ? m : 0.0f)); }

// One workgroup per batch element; state (4096 c64) in LDS; 4 gates per LDS
// round-trip; 3 passes per layer; Gray perm fused into pass-A addressing.
__global__ __launch_bounds__(TPB) void qsim_kernel(
    const float* __restrict__ x,      // (B, 12)
    const float* __restrict__ w,      // (6, 12, 3)
    const float* __restrict__ hw,     // (2, 1)
    const float* __restrict__ hb,     // (2,)
    float* __restrict__ out)          // (B, 2)
{
    __shared__ float2 st[NSTATE];     // 32 KB
    __shared__ float2 U[NL][NQ][4];
    __shared__ float  csq[NQ][2];
    __shared__ float  red[TPB / 64];

    const int b = blockIdx.x;
    const int t = threadIdx.x;

    // --- all 72 Rot matrices (threads 0..71) ---
    if (t < NL * NQ) {
        int L = t / NQ, q = t % NQ;
        const float* wl = w + (L * NQ + q) * 3;
        float phi = wl[0], th = wl[1], om = wl[2];
        float c, s, ca, sa, cb, sb;
        sincosf(0.5f * th, &s, &c);
        sincosf(0.5f * (phi + om), &sa, &ca);
        sincosf(0.5f * (phi - om), &sb, &cb);
        U[L][q][0] = make_float2( c * ca, -c * sa);   // ep*c
        U[L][q][1] = make_float2(-s * cb, -s * sb);   // -conj(em)*s
        U[L][q][2] = make_float2( s * cb, -s * sb);   // em*s
        U[L][q][3] = make_float2( c * ca,  c * sa);   // conj(ep)*c
    }
    // --- embedding angles (threads 128..139, parallel wave) ---
    if (t >= 128 && t < 128 + NQ) {
        int q = t - 128;
        float h = 0.5f * x[b * NQ + q];
        float sh, ch;
        sincosf(h, &sh, &ch);
        csq[q][0] = ch;
        csq[q][1] = sh;
    }
    __syncthreads();

    // thread-dependent address bases (loop-invariant)
    const int swzt  = t ^ (t >> 4);                       // swz(t)
    const int gt    = t ^ (t >> 1);                       // g(t)
    const int gswzt = gt ^ ((gt >> 4) & 0xF);             // swz(g(t))
    const int ptB   = ((t & 0xF0) << 4) | (t & 0x0F);
    const int ptC   = (t << 4) ^ (t & 0x0F);

    float2 a0,a1,a2,a3,a4,a5,a6,a7,a8,a9,a10,a11,a12,a13,a14,a15;

    #pragma unroll 1
    for (int L = 0; L < NL; ++L) {
        // ======== Pass A: logical i=(r<<8)|t (qubits 0..3) ========
        if (L == 0) {
            // init product state: amp_i = (-i)^popc(i) * prod(cos/sin)
            float mlow = 1.0f;
            #pragma unroll
            for (int q = 4; q < NQ; ++q)
                mlow *= csq[q][(t >> (11 - q)) & 1];
            const int pcl = __popc(t);
            INITR(0)  INITR(1)  INITR(2)  INITR(3)
            INITR(4)  INITR(5)  INITR(6)  INITR(7)
            INITR(8)  INITR(9)  INITR(10) INITR(11)
            INITR(12) INITR(13) INITR(14) INITR(15)
        } else {
            LD16(ADRA_LD)        // previous layer's Gray perm applied here
            __syncthreads();     // all reads done before any store below
        }
        GATES4(0)
        ST16(ADRA_ST)
        __syncthreads();

        // ======== Pass B: qubits 4..7 ========
        LD16(ADRB)
        GATES4(4)
        ST16(ADRB)
        __syncthreads();

        // ======== Pass C: qubits 8..11 ========
        LD16(ADRC)
        GATES4(8)
        if (L < NL - 1) {
            ST16(ADRC)
            __syncthreads();
        }
        // last layer: measure from regs; the trailing Gray perm preserves
        // state bit 11, so it cannot change <Z_0>.
    }

    // --- measurement: <Z> on qubit 0 = state bit 11 = t bit 7 ---
    float zsum = 0.0f;
    zsum += a0.x*a0.x + a0.y*a0.y;     zsum += a1.x*a1.x + a1.y*a1.y;
    zsum += a2.x*a2.x + a2.y*a2.y;     zsum += a3.x*a3.x + a3.y*a3.y;
    zsum += a4.x*a4.x + a4.y*a4.y;     zsum += a5.x*a5.x + a5.y*a5.y;
    zsum += a6.x*a6.x + a6.y*a6.y;     zsum += a7.x*a7.x + a7.y*a7.y;
    zsum += a8.x*a8.x + a8.y*a8.y;     zsum += a9.x*a9.x + a9.y*a9.y;
    zsum += a10.x*a10.x + a10.y*a10.y; zsum += a11.x*a11.x + a11.y*a11.y;
    zsum += a12.x*a12.x + a12.y*a12.y; zsum += a13.x*a13.x + a13.y*a13.y;
    zsum += a14.x*a14.x + a14.y*a14.y; zsum += a15.x*a15.x + a15.y*a15.y;

    float z = (t & 0x80) ? -zsum : zsum;
    #pragma unroll
    for (int off = 32; off >= 1; off >>= 1)
        z += __shfl_down(z, off);
    if ((t & 63) == 0) red[t >> 6] = z;
    __syncthreads();

    if (t == 0) {
        float zt = red[0] + red[1] + red[2] + red[3];
        out[2 * b + 0] = zt * hw[0] + hb[0];
        out[2 * b + 1] = zt * hw[1] + hb[1];
    }
}

extern "C" void kernel_launch(void* const* d_in, const int* in_sizes, int n_in,
                              void* d_out, int out_size, void* d_ws, size_t ws_size,
                              hipStream_t stream) {
    const float* x  = (const float*)d_in[0];
    const float* w  = (const float*)d_in[1];
    const float* hw = (const float*)d_in[2];
    const float* hb = (const float*)d_in[3];
    float* out = (float*)d_out;
    const int B = in_sizes[0] / NQ;   // 1024
    qsim_kernel<<<B, TPB, 0, stream>>>(x, w, hw, hb, out);
}

// Round 5
// 64.051 us; speedup vs baseline: 2.4773x; 1.6074x over previous
//
#include <hip/hip_runtime.h>

#define NQ 12
#define NSTATE (1 << NQ)   // 4096
#define NL 6
#define TPB 512            // 8 amps per thread (8 waves per block)

// Fixed LDS layout: phys = swz(i) = i ^ ((i>>4)&0xF). The CNOT-chain Gray
// permutation new[i] = old[g(i)], g(i)=i^(i>>1), is applied at pass-D's STORE:
// amp j is written to swz(g^-1(j)) so the next layer reads canonical layout.
// All six lane->bank-pair maps are rank-4 over the wave's lane bits =>
// conflict-free (4 lanes per bank pair = wave64 b64 minimum).

__device__ __forceinline__ void butterfly(float2& s0, float2& s1,
                                          float2 u00, float2 u01,
                                          float2 u10, float2 u11) {
    float2 n0, n1;   // 16 guaranteed v_fma/v_mul (explicit contraction)
    n0.x = fmaf(u00.x, s0.x, fmaf(-u00.y, s0.y, fmaf(u01.x, s1.x, -u01.y * s1.y)));
    n0.y = fmaf(u00.x, s0.y, fmaf( u00.y, s0.x, fmaf(u01.x, s1.y,  u01.y * s1.x)));
    n1.x = fmaf(u10.x, s0.x, fmaf(-u10.y, s0.y, fmaf(u11.x, s1.x, -u11.y * s1.y)));
    n1.y = fmaf(u10.x, s0.y, fmaf( u10.y, s0.x, fmaf(u11.x, s1.y,  u11.y * s1.x)));
    s0 = n0; s1 = n1;
}

// 8 named state registers — literal indices only => guaranteed VGPRs.
#define BF(i,j) butterfly(a##i, a##j, u00, u01, u10, u11)
#define P8K0 BF(0,1); BF(2,3); BF(4,5); BF(6,7);
#define P8K1 BF(0,2); BF(1,3); BF(4,6); BF(5,7);
#define P8K2 BF(0,4); BF(1,5); BF(2,6); BF(3,7);
#define GATE(q,P) { float2 u00 = U[L][q][0], u01 = U[L][q][1], \
                           u10 = U[L][q][2], u11 = U[L][q][3]; P }
// reg bit k <-> qubit (qb + 2 - k); same-layer 1q gates commute
#define GATES3(qb) GATE((qb)+2, P8K0) GATE((qb)+1, P8K1) GATE((qb)+0, P8K2)

#define LD8(A) { a0=st[A(0)]; a1=st[A(1)]; a2=st[A(2)]; a3=st[A(3)]; \
                 a4=st[A(4)]; a5=st[A(5)]; a6=st[A(6)]; a7=st[A(7)]; }
#define ST8(A) { st[A(0)]=a0; st[A(1)]=a1; st[A(2)]=a2; st[A(3)]=a3; \
                 st[A(4)]=a4; st[A(5)]=a5; st[A(6)]=a6; st[A(7)]=a7; }

// Pass A: i = (r<<9)|t          phys = ptA ^ (r<<9)
// Pass B: i = t[8:6]<<9|r<<6|t[5:0]  phys = ptB ^ (r<<6) ^ ((r&3)<<2)
// Pass C: i = t[8:3]<<6|r<<3|t[2:0]  phys = ptC ^ (r<<3) ^ (r>>1)
// Pass D: i = (t<<3)|r          phys = ptD ^ r
// Pass D store (g^-1 scatter):  phys = ptDs ^ ginv3(r)
#define ADRA(r)  (ptA ^ ((r) << 9))
#define ADRB(r)  (ptB ^ ((r) << 6) ^ (((r) & 3) << 2))
#define ADRC(r)  (ptC ^ ((r) << 3) ^ ((r) >> 1))
#define ADRD(r)  (ptD ^ (r))
#define GINV3(r) ((r) ^ ((r) >> 1) ^ ((r) >> 2))
#define ADRDS(r) (ptDs ^ GINV3(r))

#define INITR(r) { float m = mlow; \
    m *= csq[2][(r)&1]; m *= csq[1][((r)>>1)&1]; m *= csq[0][((r)>>2)&1]; \
    const int pc = (pcl + __popc(r)) & 3; \
    a##r = make_float2((pc==0) ? m : ((pc==2) ? -m : 0.0f), \
                       (pc==1) ? -m : ((pc==3) ? m : 0.0f)); }

__global__ __launch_bounds__(TPB, 6) void qsim_kernel(
    const float* __restrict__ x,      // (B, 12)
    const float* __restrict__ w,      // (6, 12, 3)
    const float* __restrict__ hw,     // (2, 1)
    const float* __restrict__ hb,     // (2,)
    float* __restrict__ out)          // (B, 2)
{
    __shared__ float2 st[NSTATE];     // 32 KB
    __shared__ float2 U[NL][NQ][4];   // 2.3 KB
    __shared__ float  csq[NQ][2];
    __shared__ float  red[TPB / 64];

    const int b = blockIdx.x;
    const int t = threadIdx.x;        // 9 bits

    // --- all 72 Rot matrices (threads 0..71) ---
    if (t < NL * NQ) {
        int L = t / NQ, q = t % NQ;
        const float* wl = w + (L * NQ + q) * 3;
        float phi = wl[0], th = wl[1], om = wl[2];
        float c, s, ca, sa, cb, sb;
        sincosf(0.5f * th, &s, &c);
        sincosf(0.5f * (phi + om), &sa, &ca);
        sincosf(0.5f * (phi - om), &sb, &cb);
        U[L][q][0] = make_float2( c * ca, -c * sa);   // ep*c
        U[L][q][1] = make_float2(-s * cb, -s * sb);   // -conj(em)*s
        U[L][q][2] = make_float2( s * cb, -s * sb);   // em*s
        U[L][q][3] = make_float2( c * ca,  c * sa);   // conj(ep)*c
    }
    // --- embedding angles (threads 128..139, parallel wave) ---
    if (t >= 128 && t < 128 + NQ) {
        int q = t - 128;
        float h = 0.5f * x[b * NQ + q];
        float sh, ch;
        sincosf(h, &sh, &ch);
        csq[q][0] = ch;
        csq[q][1] = sh;
    }
    __syncthreads();

    // loop-invariant address bases
    const int ptA = t ^ ((t >> 4) & 0xF);
    const int ptB = (((t & 0x1C0) << 3) | (t & 0x3F)) ^ ((t >> 4) & 0x3);
    const int ptC = (((t & 0x1F8) << 3) | (t & 0x7)) ^ (((t >> 3) & 0x3) << 2);
    const int ptD = (t << 3) ^ ((t >> 1) & 0xF);
    int gv = t << 3;                  // g^-1 = suffix-parity (GF(2)-linear)
    gv ^= gv >> 1; gv ^= gv >> 2; gv ^= gv >> 4; gv ^= gv >> 8; gv &= 0xFFF;
    const int ptDs = gv ^ ((gv >> 4) & 0xF);

    float2 a0, a1, a2, a3, a4, a5, a6, a7;

    #pragma unroll 1
    for (int L = 0; L < NL; ++L) {
        // ---- Pass A: state bits 11..9 (qubits 0..2) ----
        if (L == 0) {
            // init product state: amp_i = (-i)^popc(i) * prod(cos/sin)
            float mlow = 1.0f;
            #pragma unroll
            for (int j = 0; j < 9; ++j)          // t bit j = state bit j = qubit 11-j
                mlow *= csq[11 - j][(t >> j) & 1];
            const int pcl = __popc(t);
            INITR(0) INITR(1) INITR(2) INITR(3)
            INITR(4) INITR(5) INITR(6) INITR(7)
        } else {
            LD8(ADRA)                 // read-set == write-set: no inner barrier
        }
        GATES3(0)
        ST8(ADRA)
        __syncthreads();

        // ---- Pass B: state bits 8..6 (qubits 3..5) ----
        LD8(ADRB)
        GATES3(3)
        ST8(ADRB)
        __syncthreads();

        // ---- Pass C: state bits 5..3 (qubits 6..8) ----
        LD8(ADRC)
        GATES3(6)
        ST8(ADRC)
        __syncthreads();

        // ---- Pass D: state bits 2..0 (qubits 9..11) ----
        LD8(ADRD)
        GATES3(9)
        if (L < NL - 1) {
            ST8(ADRDS)                // Gray perm applied via g^-1 scatter
            __syncthreads();
        }
        // last layer: measure from regs (perm preserves state bit 11)
    }

    // --- measurement: <Z> on qubit 0 = state bit 11 = t bit 8 ---
    float zsum = 0.0f;
    zsum += a0.x*a0.x + a0.y*a0.y;  zsum += a1.x*a1.x + a1.y*a1.y;
    zsum += a2.x*a2.x + a2.y*a2.y;  zsum += a3.x*a3.x + a3.y*a3.y;
    zsum += a4.x*a4.x + a4.y*a4.y;  zsum += a5.x*a5.x + a5.y*a5.y;
    zsum += a6.x*a6.x + a6.y*a6.y;  zsum += a7.x*a7.x + a7.y*a7.y;

    float z = (t & 0x100) ? -zsum : zsum;
    #pragma unroll
    for (int off = 32; off >= 1; off >>= 1)
        z += __shfl_down(z, off);
    if ((t & 63) == 0) red[t >> 6] = z;
    __syncthreads();

    if (t == 0) {
        float zt = 0.0f;
        #pragma unroll
        for (int wv = 0; wv < TPB / 64; ++wv) zt += red[wv];
        out[2 * b + 0] = zt * hw[0] + hb[0];
        out[2 * b + 1] = zt * hw[1] + hb[1];
    }
}

extern "C" void kernel_launch(void* const* d_in, const int* in_sizes, int n_in,
                              void* d_out, int out_size, void* d_ws, size_t ws_size,
                              hipStream_t stream) {
    const float* x  = (const float*)d_in[0];
    const float* w  = (const float*)d_in[1];
    const float* hw = (const float*)d_in[2];
    const float* hb = (const float*)d_in[3];
    float* out = (float*)d_out;
    const int B = in_sizes[0] / NQ;   // 1024
    qsim_kernel<<<B, TPB, 0, stream>>>(x, w, hw, hb, out);
}

// Round 6
// 63.364 us; speedup vs baseline: 2.5042x; 1.0108x over previous
//
#include <hip/hip_runtime.h>

#define NQ 12
#define NSTATE (1 << NQ)   // 4096
#define NL 6
#define TPB 512            // 8 amps/thread, 8 waves/block

// LDS = state only (exactly 32768 B) to maximize blocks/CU.
// Layout: phys = swz(i) = i ^ ((i>>6)&7) ^ ((i&0x40)>>3).
// Rank-checked lane->bank-pair maps: passes A,B,C,D ld/st all rank-4
// (conflict-free); D's g^-1 scatter rank-3 (2x on 8 stores/layer, accepted).
// Gate matrices live in lane-slots of VGPRs, broadcast via v_readlane ->
// SGPR operands (no LDS, no lgkm waits in the gate loop).

__device__ __forceinline__ float RL(float v, int idx) {
    return __int_as_float(__builtin_amdgcn_readlane(__float_as_int(v), idx));
}

// Rot(phi,theta,omega): u00=(A,-B) u01=(-C,-D) u10=(C,-D) u11=(A,B)
// A=c*ca B=c*sa C=s*cb D=s*sb (a=(phi+om)/2, b=(phi-om)/2, c/s = cos/sin th/2)
__device__ __forceinline__ void bf_sg(float2& s0, float2& s1,
                                      float A, float B, float C, float D) {
    float2 n0, n1;
    n0.x = fmaf(A, s0.x, fmaf( B, s0.y, fmaf(-C, s1.x,  D * s1.y)));
    n0.y = fmaf(A, s0.y, fmaf(-B, s0.x, fmaf(-C, s1.y, -D * s1.x)));
    n1.x = fmaf(C, s0.x, fmaf( D, s0.y, fmaf( A, s1.x, -B * s1.y)));
    n1.y = fmaf(C, s0.y, fmaf(-D, s0.x, fmaf( A, s1.y,  B * s1.x)));
    s0 = n0; s1 = n1;
}

#define BF(i,j) bf_sg(a##i, a##j, A, B, C, D)
#define P8K0 BF(0,1); BF(2,3); BF(4,5); BF(6,7);
#define P8K1 BF(0,2); BF(1,3); BF(4,6); BF(5,7);
#define P8K2 BF(0,4); BF(1,5); BF(2,6); BF(3,7);
// gate qq of current layer, constants broadcast from lane gb+qq
#define GATE(qq, P) { const int gi = gb + (qq); \
    const float A = RL(uA, gi), B = RL(uB, gi), \
                C = RL(uC, gi), D = RL(uD, gi); P }

#define LD8(ADR) { a0=st[ADR(0)]; a1=st[ADR(1)]; a2=st[ADR(2)]; a3=st[ADR(3)]; \
                   a4=st[ADR(4)]; a5=st[ADR(5)]; a6=st[ADR(6)]; a7=st[ADR(7)]; }
#define ST8(ADR) { st[ADR(0)]=a0; st[ADR(1)]=a1; st[ADR(2)]=a2; st[ADR(3)]=a3; \
                   st[ADR(4)]=a4; st[ADR(5)]=a5; st[ADR(6)]=a6; st[ADR(7)]=a7; }

// Pass tilings (i = logical state index, t = 9-bit thread, r = 3-bit reg):
// A: i=(r<<9)|t            B: i=t[8:6]<<9 | r<<6 | t[5:0]
// C: i=t[8:3]<<6 | r<<3 | t[2:0]            D: i=(t<<3)|r
#define ADRA(r)  (ptA + ((r) << 9))                              // offset-imm
#define ADRB(r)  (ptB ^ ((r) << 6) ^ (r) ^ (((r) & 1) << 3))
#define ADRC(r)  (ptC ^ ((r) << 3))
#define ADRD(r)  (ptD ^ (r))
#define GINV3(r) ((r) ^ ((r) >> 1) ^ ((r) >> 2))
#define ADRDS(r) (ptDS ^ GINV3(r))                               // g^-1 scatter

// init product state (pass-A tiling): reg bit k <-> qubit 2-k
#define INITR(r) { const float m = mlow * f##r; \
    const int pc = (pcl + __popc(r)) & 3; \
    a##r = make_float2((pc==0) ? m : ((pc==2) ? -m : 0.0f), \
                       (pc==1) ? -m : ((pc==3) ? m : 0.0f)); }

__global__ __launch_bounds__(TPB) void qsim_kernel(
    const float* __restrict__ x,      // (B, 12)
    const float* __restrict__ w,      // (6, 12, 3)
    const float* __restrict__ hw,     // (2, 1)
    const float* __restrict__ hb,     // (2,)
    float* __restrict__ out)          // (B, 2)
{
    __shared__ float2 st[NSTATE];     // exactly 32768 B, nothing else in LDS

    const int b = blockIdx.x;
    const int t = threadIdx.x;        // 9 bits
    const int lane = t & 63;

    // ---- prologue: all 72 gate-constant quads into lane slots ----
    // lane j (0..63): gate j.  lanes 52..63 second set: gates 60..71.
    float gA, gB, gC, gD;
    float gA2 = 0.f, gB2 = 0.f, gC2 = 0.f, gD2 = 0.f;
    {
        const float* wl = w + lane * 3;
        float phi = wl[0], th = wl[1], om = wl[2];
        float c, s, ca, sa, cb, sb;
        __sincosf(0.5f * th, &s, &c);
        __sincosf(0.5f * (phi + om), &sa, &ca);
        __sincosf(0.5f * (phi - om), &sb, &cb);
        gA = c * ca; gB = c * sa; gC = s * cb; gD = s * sb;
        if (lane >= 52) {
            const float* wl2 = w + (lane + 8) * 3;
            float phi2 = wl2[0], th2 = wl2[1], om2 = wl2[2];
            float c2, s2q, ca2, sa2, cb2, sb2;
            __sincosf(0.5f * th2, &s2q, &c2);
            __sincosf(0.5f * (phi2 + om2), &sa2, &ca2);
            __sincosf(0.5f * (phi2 - om2), &sb2, &cb2);
            gA2 = c2 * ca2; gB2 = c2 * sa2; gC2 = s2q * cb2; gD2 = s2q * sb2;
        }
    }

    // ---- loop-invariant address bases (phys = swz(i)) ----
    const int ptA  = t ^ ((t >> 6) & 7) ^ ((t & 0x40) >> 3);
    const int ptB  = ((t & 0x1C0) << 3) | (t & 0x3F);
    const int ptC  = (((t >> 3) << 6) | (t & 7)) ^ ((t >> 3) & 7)
                     ^ (((t >> 3) & 1) << 3);
    const int ptD  = (t << 3) ^ ((t >> 3) & 7) ^ (((t >> 3) & 1) << 3);
    int gv = t << 3;                  // g^-1 = suffix parity (GF(2)-linear)
    gv ^= gv >> 1; gv ^= gv >> 2; gv ^= gv >> 4; gv ^= gv >> 8; gv &= 0xFFF;
    const int ptDS = gv ^ ((gv >> 6) & 7) ^ ((gv & 0x40) >> 3);

    float2 a0, a1, a2, a3, a4, a5, a6, a7;

    #pragma unroll 1
    for (int L = 0; L < NL; ++L) {
        const int   gb = (L == 5) ? 52 : L * 12;
        const float uA = (L == 5) ? gA2 : gA;
        const float uB = (L == 5) ? gB2 : gB;
        const float uC = (L == 5) ? gC2 : gC;
        const float uD = (L == 5) ? gD2 : gD;

        // ---- Pass A: state bits 11..9 (qubits 0..2) ----
        if (L == 0) {
            // per-thread embedding sincos + product state in regs
            float c0,s0,c1,s1,c2,s2,c3,s3,c4,s4,c5,s5;
            float c6,s6,c7,s7,c8,s8,c9,s9,c10,s10,c11,s11;
            #define EMB(q) __sincosf(0.5f * x[b * NQ + (q)], &s##q, &c##q);
            EMB(0) EMB(1) EMB(2) EMB(3) EMB(4)  EMB(5)
            EMB(6) EMB(7) EMB(8) EMB(9) EMB(10) EMB(11)
            #undef EMB
            // t bit j = state bit j <-> qubit 11-j
            float mlow = ((t & 1)   ? s11 : c11) * ((t & 2)   ? s10 : c10);
            mlow *= ((t & 4)   ? s9 : c9) * ((t & 8)   ? s8 : c8);
            mlow *= ((t & 16)  ? s7 : c7) * ((t & 32)  ? s6 : c6);
            mlow *= ((t & 64)  ? s5 : c5) * ((t & 128) ? s4 : c4);
            mlow *= ((t & 256) ? s3 : c3);
            // reg bit k <-> qubit 2-k
            const float e0 = c1 * c0, e1 = s1 * c0, e2 = c1 * s0, e3 = s1 * s0;
            const float f0 = c2 * e0, f1 = s2 * e0, f2 = c2 * e1, f3 = s2 * e1;
            const float f4 = c2 * e2, f5 = s2 * e2, f6 = c2 * e3, f7 = s2 * e3;
            const int pcl = __popc(t);
            INITR(0) INITR(1) INITR(2) INITR(3)
            INITR(4) INITR(5) INITR(6) INITR(7)
        } else {
            LD8(ADRA)                 // rd == wr set per thread: no mid barrier
        }
        GATE(2, P8K0) GATE(1, P8K1) GATE(0, P8K2)
        ST8(ADRA)
        __syncthreads();

        // ---- Pass B: state bits 8..6 (qubits 3..5) ----
        LD8(ADRB)
        GATE(5, P8K0) GATE(4, P8K1) GATE(3, P8K2)
        ST8(ADRB)
        __syncthreads();

        // ---- Pass C: state bits 5..3 (qubits 6..8) ----
        LD8(ADRC)
        GATE(8, P8K0) GATE(7, P8K1) GATE(6, P8K2)
        ST8(ADRC)
        __syncthreads();

        // ---- Pass D: state bits 2..0 (qubits 9..11) ----
        LD8(ADRD)
        GATE(11, P8K0) GATE(10, P8K1) GATE(9, P8K2)
        if (L < NL - 1) {
            __syncthreads();          // ALL pass-D reads done before scatter
            ST8(ADRDS)                // Gray perm via g^-1 scatter
            __syncthreads();
        }
        // last layer: measure from regs (trailing perm preserves bit 11)
    }

    // ---- measurement: <Z> on qubit 0 = state bit 11 = t bit 8 ----
    float zsum = 0.0f;
    zsum += a0.x*a0.x + a0.y*a0.y;  zsum += a1.x*a1.x + a1.y*a1.y;
    zsum += a2.x*a2.x + a2.y*a2.y;  zsum += a3.x*a3.x + a3.y*a3.y;
    zsum += a4.x*a4.x + a4.y*a4.y;  zsum += a5.x*a5.x + a5.y*a5.y;
    zsum += a6.x*a6.x + a6.y*a6.y;  zsum += a7.x*a7.x + a7.y*a7.y;

    float z = (t & 256) ? -zsum : zsum;
    #pragma unroll
    for (int off = 32; off >= 1; off >>= 1)
        z += __shfl_down(z, off);

    __syncthreads();                  // all pass-D reads done before st reuse
    float* red = (float*)st;
    if (lane == 0) red[t >> 6] = z;
    __syncthreads();

    if (t == 0) {
        float zt = 0.0f;
        #pragma unroll
        for (int wv = 0; wv < TPB / 64; ++wv) zt += red[wv];
        out[2 * b + 0] = zt * hw[0] + hb[0];
        out[2 * b + 1] = zt * hw[1] + hb[1];
    }
}

extern "C" void kernel_launch(void* const* d_in, const int* in_sizes, int n_in,
                              void* d_out, int out_size, void* d_ws, size_t ws_size,
                              hipStream_t stream) {
    const float* x  = (const float*)d_in[0];
    const float* w  = (const float*)d_in[1];
    const float* hw = (const float*)d_in[2];
    const float* hb = (const float*)d_in[3];
    float* out = (float*)d_out;
    const int B = in_sizes[0] / NQ;   // 1024
    qsim_kernel<<<B, TPB, 0, stream>>>(x, w, hw, hb, out);
}